// Round 17
// baseline (626.492 us; speedup 1.0000x reference)
//
#include <hip/hip_runtime.h>
#include <hip/hip_bf16.h>

#define NNODES 100000
#define NEDGES 3200000
#define INF 128
#define HID 32
#define MID 50000                              // src-range split point
#define NB 392                                 // buckets: node>>8, 256 nodes each
#define BSHIFT 8
#define NPB 256                                // nodes per bucket
#define BATCH 8192                             // edges per partition block
#define PART_BLOCKS ((NEDGES + BATCH - 1) / BATCH)  // 391
#define G1_ROWS 256                            // gemm1 rows per block
#define G1_KC 16                               // gemm1 k-chunk
#define G1_XP 260                              // padded xT row

typedef unsigned short u16;
typedef float f4v __attribute__((ext_vector_type(4)));

__device__ __forceinline__ float blo(unsigned x) { return __uint_as_float(x << 16); }
__device__ __forceinline__ float bhi(unsigned x) { return __uint_as_float(x & 0xffff0000u); }
__device__ __forceinline__ u16 f2b(float f) {
    __hip_bfloat16 h = __float2bfloat16(f);    // RNE
    return *reinterpret_cast<u16*>(&h);
}
__device__ __forceinline__ void nt_store4(float* p, float a, float b, float c, float d) {
    f4v v = {a, b, c, d};
    __builtin_nontemporal_store(v, (f4v*)p);
}
__device__ __forceinline__ f4v nt_load4(const float* p) {
    return __builtin_nontemporal_load((const f4v*)p);
}

// ---- pass 1: per-block LDS bucket histograms -> global bucket counts ----
__global__ void k_cnt(const int* __restrict__ src, const int* __restrict__ dst,
                      int* __restrict__ bcnt_src, int* __restrict__ bcnt_dst) {
    __shared__ int hs[NB], hd[NB];
    int tid = threadIdx.x;
    for (int i = tid; i < NB; i += 1024) { hs[i] = 0; hd[i] = 0; }
    __syncthreads();
    int start = blockIdx.x * BATCH;
    int end = start + BATCH; if (end > NEDGES) end = NEDGES;
    for (int i = start + tid; i < end; i += 1024) {
        atomicAdd(&hs[src[i] >> BSHIFT], 1);
        atomicAdd(&hd[dst[i] >> BSHIFT], 1);
    }
    __syncthreads();
    for (int i = tid; i < NB; i += 1024) {
        if (hs[i]) atomicAdd(&bcnt_src[i], hs[i]);
        if (hd[i]) atomicAdd(&bcnt_dst[i], hd[i]);
    }
}

// ---- pass 2: exclusive scan of the NB-entry bucket counts (both sides) ----
__global__ void k_bscan(const int* __restrict__ bcnt_src, const int* __restrict__ bcnt_dst,
                        int* __restrict__ bbase_src, int* __restrict__ bbase_dst,
                        int* __restrict__ gcur_src, int* __restrict__ gcur_dst) {
    __shared__ int s[512], t[512];
    int tid = threadIdx.x;
    int vs = (tid < NB) ? bcnt_src[tid] : 0;
    int vd = (tid < NB) ? bcnt_dst[tid] : 0;
    s[tid] = vs; t[tid] = vd;
    __syncthreads();
    for (int off = 1; off < 512; off <<= 1) {
        int a = (tid >= off) ? s[tid - off] : 0;
        int b = (tid >= off) ? t[tid - off] : 0;
        __syncthreads();
        s[tid] += a; t[tid] += b;
        __syncthreads();
    }
    if (tid < NB) {
        bbase_src[tid] = s[tid] - vs;  gcur_src[tid] = s[tid] - vs;
        bbase_dst[tid] = t[tid] - vd;  gcur_dst[tid] = t[tid] - vd;
    }
}

// ---- pass 3: LDS-staged bucket partition (round-14 known-good) ----
__global__ void k_bucket2(const int* __restrict__ src, const int* __restrict__ dst,
                          int* __restrict__ gcur_src, int* __restrict__ gcur_dst,
                          int2* __restrict__ pairbuf, int* __restrict__ srctmp) {
    __shared__ int2 stage2[BATCH];             // 64 KB (phase B reuses as int[])
    __shared__ int cnt[NB], excl[NB], gbase[NB];
    __shared__ int sc[512];
    int* stage1 = (int*)stage2;
    int tid = threadIdx.x;                     // 1024 threads
    int start = blockIdx.x * BATCH;
    int end = start + BATCH; if (end > NEDGES) end = NEDGES;
    int cntE = end - start;

    int dd[8], sv[8], rk[8];

    // ================= Phase A: dst-bucketed (dst,src) pairs =================
    for (int i = tid; i < NB; i += 1024) cnt[i] = 0;
    __syncthreads();
#pragma unroll
    for (int k = 0; k < 8; ++k) {
        int i = start + tid + k * 1024;
        dd[k] = -1;
        if (i < end) {
            dd[k] = dst[i]; sv[k] = src[i];
            rk[k] = atomicAdd(&cnt[dd[k] >> BSHIFT], 1);
        }
    }
    __syncthreads();
    if (tid < 512) sc[tid] = (tid < NB) ? cnt[tid] : 0;
    __syncthreads();
    for (int off = 1; off < 512; off <<= 1) {
        int v = (tid < 512 && tid >= off) ? sc[tid - off] : 0;
        __syncthreads();
        if (tid < 512) sc[tid] += v;
        __syncthreads();
    }
    if (tid < NB) {
        excl[tid] = sc[tid] - cnt[tid];
        int c = cnt[tid];
        gbase[tid] = c ? atomicAdd(&gcur_dst[tid], c) : 0;
    }
    __syncthreads();
#pragma unroll
    for (int k = 0; k < 8; ++k)
        if (dd[k] >= 0) {
            int2 e; e.x = dd[k]; e.y = sv[k];
            stage2[excl[dd[k] >> BSHIFT] + rk[k]] = e;
        }
    __syncthreads();
    for (int j = tid; j < cntE; j += 1024) {
        int2 e = stage2[j];
        int b = e.x >> BSHIFT;
        pairbuf[gbase[b] + (j - excl[b])] = e;
    }
    __syncthreads();

    // ================= Phase B: src-bucketed src values ======================
    for (int i = tid; i < NB; i += 1024) cnt[i] = 0;
    __syncthreads();
#pragma unroll
    for (int k = 0; k < 8; ++k)
        if (dd[k] >= 0)
            rk[k] = atomicAdd(&cnt[sv[k] >> BSHIFT], 1);
    __syncthreads();
    if (tid < 512) sc[tid] = (tid < NB) ? cnt[tid] : 0;
    __syncthreads();
    for (int off = 1; off < 512; off <<= 1) {
        int v = (tid < 512 && tid >= off) ? sc[tid - off] : 0;
        __syncthreads();
        if (tid < 512) sc[tid] += v;
        __syncthreads();
    }
    if (tid < NB) {
        excl[tid] = sc[tid] - cnt[tid];
        int c = cnt[tid];
        gbase[tid] = c ? atomicAdd(&gcur_src[tid], c) : 0;
    }
    __syncthreads();
#pragma unroll
    for (int k = 0; k < 8; ++k)
        if (dd[k] >= 0)
            stage1[excl[sv[k] >> BSHIFT] + rk[k]] = sv[k];
    __syncthreads();
    for (int j = tid; j < cntE; j += 1024) {
        int v = stage1[j];
        int b = v >> BSHIFT;
        srctmp[gbase[b] + (j - excl[b])] = v;
    }
}

// ---- pass 4: per-bucket node stats + per-row low/high split pointer rowmid ----
__global__ void k_nodes(const int* __restrict__ srctmp, const int2* __restrict__ pairbuf,
                        const int* __restrict__ bbase_src, const int* __restrict__ bcnt_src,
                        const int* __restrict__ bbase_dst, const int* __restrict__ bcnt_dst,
                        float* __restrict__ out_norm, float* __restrict__ in_norm,
                        int* __restrict__ indeg, int* __restrict__ rowstart,
                        int* __restrict__ rowmid) {
    __shared__ int cnt[NPB];
    __shared__ int cntlow[NPB];
    __shared__ int ss[NPB];
    int tid = threadIdx.x;
    int b = blockIdx.x;
    int srcphase = (b < NB);
    int bb = srcphase ? b : b - NB;
    int node0 = bb * NPB;
    cnt[tid] = 0; cntlow[tid] = 0;
    __syncthreads();
    if (srcphase) {
        int s0 = bbase_src[bb], n = bcnt_src[bb];
        for (int i = tid; i < n; i += 256)
            atomicAdd(&cnt[srctmp[s0 + i] - node0], 1);
        __syncthreads();
        int nn = node0 + tid;
        if (nn < NNODES) {
            int c = cnt[tid];
            out_norm[nn] = rsqrtf((float)(c > 1 ? c : 1));
        }
    } else {
        int d0 = bbase_dst[bb], n = bcnt_dst[bb];
        for (int i = tid; i < n; i += 256) {
            int2 e = pairbuf[d0 + i];
            atomicAdd(&cnt[e.x - node0], 1);
            if (e.y < MID) atomicAdd(&cntlow[e.x - node0], 1);
        }
        __syncthreads();
        int c = cnt[tid];
        ss[tid] = c;
        __syncthreads();
        for (int off = 1; off < 256; off <<= 1) {
            int t = (tid >= off) ? ss[tid - off] : 0;
            __syncthreads();
            ss[tid] += t;
            __syncthreads();
        }
        int excl = ss[tid] - c;
        int nn = node0 + tid;
        if (nn < NNODES) {
            indeg[nn] = c;
            in_norm[nn] = rsqrtf((float)(c > 1 ? c : 1));
            rowstart[nn] = d0 + excl;
            rowmid[nn]   = d0 + excl + cntlow[tid];
        }
    }
}

// ---- pass 5: within-bucket placement with low/high partition per row ----
__global__ void k_place(const int2* __restrict__ pairbuf, const int* __restrict__ rowstart,
                        const int* __restrict__ rowmid, int* __restrict__ col) {
    __shared__ int curlo[NPB], curhi[NPB];
    int tid = threadIdx.x;
    int bucket = blockIdx.x;
    int node0 = bucket * NPB;
    if (node0 >= NNODES) return;
    int n = node0 + tid;
    curlo[tid] = (n < NNODES) ? rowstart[n] : 0;
    curhi[tid] = (n < NNODES) ? rowmid[n] : 0;
    __syncthreads();
    int pstart = rowstart[node0];
    int pend   = (node0 + NPB >= NNODES) ? NEDGES : rowstart[node0 + NPB];
    for (int i = pstart + tid; i < pend; i += 256) {
        int2 e = pairbuf[i];
        int j = e.x - node0;
        int pos = (e.y < MID) ? atomicAdd(&curlo[j], 1) : atomicAdd(&curhi[j], 1);
        col[pos] = e.y;
    }
}

// ---- conv1 dense: register-blocked (round-16 known-good) ----
__global__ __launch_bounds__(256) void k_gemm1(const float* __restrict__ x,
                                               const float* __restrict__ W1,
                                               const float* __restrict__ out_norm,
                                               u16* __restrict__ t) {
    __shared__ float wlds[INF * HID];          // 16 KB, [k][c]
    __shared__ float xT[G1_KC][G1_XP];         // 16.6 KB, transposed x chunk
    int tid = threadIdx.x;
    int row0 = blockIdx.x * G1_ROWS;
    for (int i = tid; i < INF * HID; i += 256) wlds[i] = W1[i];

    int rg = tid >> 2;                         // 0..63: row-group (4 rows)
    int cg = tid & 3;                          // 0..3: col-group (8 cols)
    int sr = tid >> 2;
    int kq = tid & 3;

    float acc[4][8];
#pragma unroll
    for (int r = 0; r < 4; ++r)
#pragma unroll
        for (int c = 0; c < 8; ++c) acc[r][c] = 0.f;

    for (int kc = 0; kc < INF; kc += G1_KC) {
#pragma unroll
        for (int pass = 0; pass < 4; ++pass) {
            int r = pass * 64 + sr;
            int grow = row0 + r;
            float4 xv = make_float4(0.f, 0.f, 0.f, 0.f);
            if (grow < NNODES)
                xv = *(const float4*)(x + (size_t)grow * INF + kc + kq * 4);
            xT[kq * 4 + 0][r] = xv.x;
            xT[kq * 4 + 1][r] = xv.y;
            xT[kq * 4 + 2][r] = xv.z;
            xT[kq * 4 + 3][r] = xv.w;
        }
        __syncthreads();
#pragma unroll
        for (int kk = 0; kk < G1_KC; ++kk) {
            float4 xr = *(const float4*)&xT[kk][rg * 4];
            float4 wa = *(const float4*)&wlds[(kc + kk) * HID + cg * 8];
            float4 wb = *(const float4*)&wlds[(kc + kk) * HID + cg * 8 + 4];
            float xs[4] = {xr.x, xr.y, xr.z, xr.w};
#pragma unroll
            for (int r = 0; r < 4; ++r) {
                acc[r][0] = fmaf(xs[r], wa.x, acc[r][0]);
                acc[r][1] = fmaf(xs[r], wa.y, acc[r][1]);
                acc[r][2] = fmaf(xs[r], wa.z, acc[r][2]);
                acc[r][3] = fmaf(xs[r], wa.w, acc[r][3]);
                acc[r][4] = fmaf(xs[r], wb.x, acc[r][4]);
                acc[r][5] = fmaf(xs[r], wb.y, acc[r][5]);
                acc[r][6] = fmaf(xs[r], wb.z, acc[r][6]);
                acc[r][7] = fmaf(xs[r], wb.w, acc[r][7]);
            }
        }
        __syncthreads();
    }
#pragma unroll
    for (int r = 0; r < 4; ++r) {
        int row = row0 + rg * 4 + r;
        if (row < NNODES) {
            float on = out_norm[row];
            unsigned p0 = f2b(acc[r][0] * on) | ((unsigned)f2b(acc[r][1] * on) << 16);
            unsigned p1 = f2b(acc[r][2] * on) | ((unsigned)f2b(acc[r][3] * on) << 16);
            unsigned p2 = f2b(acc[r][4] * on) | ((unsigned)f2b(acc[r][5] * on) << 16);
            unsigned p3 = f2b(acc[r][6] * on) | ((unsigned)f2b(acc[r][7] * on) << 16);
            *(uint4*)(t + (size_t)row * HID + cg * 8) = make_uint4(p0, p1, p2, p3);
        }
    }
}

// ---- fused SpMM, src-range split. RANGE=0: edges with src<MID (gather window =
// 3.2MB contiguous, fits per-XCD 4MB L2, temporally separated by launch boundary),
// raw partial sum -> f32 P[N][32] (nt stores). RANGE=1: edges with src>=MID,
// combine with P, *in_norm, optional W+bias, epilogue. Each edge visited once
// across the pair (per-row rowmid split), so total requests unchanged but each
// launch's gather is L2-resident -> miss-latency (MSHR) bound relaxed.
template<int RANGE, int APPLY_W, int FINAL>
__global__ void k_spmm(const u16* __restrict__ gin, const int* __restrict__ rowstart,
                       const int* __restrict__ rowmid, const int* __restrict__ indeg,
                       const int* __restrict__ col, const float* __restrict__ in_norm,
                       const float* __restrict__ out_norm, const float* __restrict__ W,
                       const float* __restrict__ bias, float* __restrict__ P,
                       void* __restrict__ gout) {
    __shared__ float wlds[HID * HID];          // 4 KB (RANGE=1 APPLY_W only)
    __shared__ float sh[8][HID];
    int tid = threadIdx.x, lane = tid & 31, group = tid >> 5;
    int g = lane >> 2, f = lane & 3;
    if (RANGE == 1 && APPLY_W) {
        for (int i = tid; i < HID * HID; i += 256) wlds[i] = W[i];
        __syncthreads();
    }
    int n = blockIdx.x * 8 + group;            // grid = N/8 exact
    int start, deg;
    if (RANGE == 0) { start = rowstart[n]; deg = rowmid[n] - start; }
    else            { start = rowmid[n];   deg = rowstart[n] + indeg[n] - start; }
    const uint4* gin16 = (const uint4*)gin;    // 16B = 8 bf16

    float a[8];
#pragma unroll
    for (int j = 0; j < 8; ++j) a[j] = 0.f;

    int base = 0;
    for (; base + 32 <= deg; base += 32) {     // full chunks: no predication
        int c = __builtin_nontemporal_load(&col[start + base + lane]);
#pragma unroll
        for (int t = 0; t < 4; ++t) {
            int s = __shfl(c, t * 8 + g, 32);
            uint4 v = gin16[(size_t)s * 4 + f];
            a[0] += blo(v.x); a[1] += bhi(v.x);
            a[2] += blo(v.y); a[3] += bhi(v.y);
            a[4] += blo(v.z); a[5] += bhi(v.z);
            a[6] += blo(v.w); a[7] += bhi(v.w);
        }
    }
    if (base < deg) {                          // tail chunk (rem in 1..31)
        int rem = deg - base;
        int c = (base + lane < deg)
              ? __builtin_nontemporal_load(&col[start + base + lane]) : 0;
#pragma unroll
        for (int t = 0; t < 4; ++t) {
            if (t * 8 < rem) {
                int e = t * 8 + g;
                int s = __shfl(c, e, 32);
                uint4 v = gin16[(size_t)s * 4 + f];
                float m = (e < rem) ? 1.f : 0.f;
                a[0] = fmaf(m, blo(v.x), a[0]); a[1] = fmaf(m, bhi(v.x), a[1]);
                a[2] = fmaf(m, blo(v.y), a[2]); a[3] = fmaf(m, bhi(v.y), a[3]);
                a[4] = fmaf(m, blo(v.z), a[4]); a[5] = fmaf(m, bhi(v.z), a[5]);
                a[6] = fmaf(m, blo(v.w), a[6]); a[7] = fmaf(m, bhi(v.w), a[7]);
            }
        }
    }
    // reduce across the 8 edge-subgroups (lane bits 2,3,4)
#pragma unroll
    for (int j = 0; j < 8; ++j) {
        a[j] += __shfl_xor(a[j], 4, 32);
        a[j] += __shfl_xor(a[j], 8, 32);
        a[j] += __shfl_xor(a[j], 16, 32);
    }
    if (RANGE == 0) {                          // raw partial sum -> P, done
        if (g == 0) {
            nt_store4(&P[(size_t)n * HID + f * 8],     a[0], a[1], a[2], a[3]);
            nt_store4(&P[(size_t)n * HID + f * 8 + 4], a[4], a[5], a[6], a[7]);
        }
        return;
    }
    // RANGE == 1: combine with P, scale, epilogue
    float inm = in_norm[n];
    if (g == 0) {
        f4v plo = nt_load4(&P[(size_t)n * HID + f * 8]);
        f4v phi = nt_load4(&P[(size_t)n * HID + f * 8 + 4]);
        float4 lo = make_float4((a[0] + plo.x) * inm, (a[1] + plo.y) * inm,
                                (a[2] + plo.z) * inm, (a[3] + plo.w) * inm);
        float4 hi = make_float4((a[4] + phi.x) * inm, (a[5] + phi.y) * inm,
                                (a[6] + phi.z) * inm, (a[7] + phi.w) * inm);
        *(float4*)&sh[group][f * 8]     = lo;  // same-wave LDS fill
        *(float4*)&sh[group][f * 8 + 4] = hi;
    }
    float res;
    if (APPLY_W) {
        float o = bias[lane];
#pragma unroll
        for (int k = 0; k < HID; ++k)
            o += sh[group][k] * wlds[k * HID + lane];
        res = o;
    } else {
        res = sh[group][lane] + bias[lane];
    }
    if (FINAL) ((float*)gout)[(size_t)n * HID + lane] = res;
    else       ((u16*)gout)[(size_t)n * HID + lane] = f2b(res * out_norm[n]);
}

extern "C" void kernel_launch(void* const* d_in, const int* in_sizes, int n_in,
                              void* d_out, int out_size, void* d_ws, size_t ws_size,
                              hipStream_t stream) {
    const float* in_feat = (const float*)d_in[0];
    const float* W1      = (const float*)d_in[1];
    const float* b1      = (const float*)d_in[2];
    const float* W2      = (const float*)d_in[3];
    const float* b2      = (const float*)d_in[4];
    const int*   src     = (const int*)d_in[5];
    const int*   dst     = (const int*)d_in[6];
    float*       out     = (float*)d_out;

    const int N = NNODES, E = NEDGES;
    // workspace layout (4-byte units)
    int* bcnt_src  = (int*)d_ws;                // 512
    int* bcnt_dst  = bcnt_src + 512;            // 512
    int* bbase_src = bcnt_dst + 512;            // 512
    int* bbase_dst = bbase_src + 512;           // 512
    int* gcur_src  = bbase_dst + 512;           // 512
    int* gcur_dst  = gcur_src + 512;            // 512
    int* indeg     = gcur_dst + 512;            // N
    int* rowstart  = indeg + N;                 // N
    int* rowmid    = rowstart + N;              // N
    float* out_norm = (float*)(rowmid + N);     // N
    float* in_norm  = out_norm + N;             // N
    int*   col      = (int*)(in_norm + N);      // E   (aliased as srctmp pre-place)
    void*  bufreg   = (void*)(col + E);         // E int2 = 25.6MB region
    int2*  pairbuf  = (int2*)bufreg;            // E pairs (build phase only)
    int*   srctmp   = col;                      // E ints, consumed before col written
    u16*   bufA16   = (u16*)bufreg;             // N*HID bf16 (6.4MB)
    u16*   bufB16   = bufA16 + (size_t)N * HID; // N*HID bf16 (6.4MB)
    float* Pf32     = (float*)(bufA16 + (size_t)2 * N * HID);  // N*HID f32 (12.8MB slack)
    size_t need = ((size_t)3072 + 5 * N + E + (size_t)2 * N * HID) * 4;
    if (ws_size < need) return;                 // fail visibly rather than corrupt

    hipMemsetAsync(bcnt_src, 0, 1024 * sizeof(int), stream);  // bcnt_src + bcnt_dst

    k_cnt    <<<PART_BLOCKS, 1024, 0, stream>>>(src, dst, bcnt_src, bcnt_dst);
    k_bscan  <<<1, 512, 0, stream>>>(bcnt_src, bcnt_dst, bbase_src, bbase_dst,
                                     gcur_src, gcur_dst);
    k_bucket2<<<PART_BLOCKS, 1024, 0, stream>>>(src, dst, gcur_src, gcur_dst,
                                                pairbuf, srctmp);
    k_nodes  <<<2 * NB, 256, 0, stream>>>(srctmp, pairbuf, bbase_src, bcnt_src,
                                          bbase_dst, bcnt_dst, out_norm, in_norm,
                                          indeg, rowstart, rowmid);
    k_place  <<<NB, 256, 0, stream>>>(pairbuf, rowstart, rowmid, col);

    // conv1 dense projection (weight_first since 128>32), bf16 output
    k_gemm1<<<(N + G1_ROWS - 1) / G1_ROWS, 256, 0, stream>>>(in_feat, W1, out_norm, bufA16);

    const int G = N / 8;
    // conv1 aggregate: bufA -> bufB (no W), pre-scaled by out_norm
    k_spmm<0, 0, 0><<<G, 256, 0, stream>>>(bufA16, rowstart, rowmid, indeg, col,
                                           in_norm, out_norm, W2, b1, Pf32, bufB16);
    k_spmm<1, 0, 0><<<G, 256, 0, stream>>>(bufA16, rowstart, rowmid, indeg, col,
                                           in_norm, out_norm, W2, b1, Pf32, bufB16);

    // 6 middle convs: ping-pong B->A->B->...
    u16* cur = bufB16; u16* nxt = bufA16;
    for (int i = 0; i < 6; ++i) {
        k_spmm<0, 1, 0><<<G, 256, 0, stream>>>(cur, rowstart, rowmid, indeg, col,
                                               in_norm, out_norm, W2, b2, Pf32, nxt);
        k_spmm<1, 1, 0><<<G, 256, 0, stream>>>(cur, rowstart, rowmid, indeg, col,
                                               in_norm, out_norm, W2, b2, Pf32, nxt);
        u16* tmp = cur; cur = nxt; nxt = tmp;
    }
    // final conv: cur -> out (f32, no out_norm pre-scale)
    k_spmm<0, 1, 1><<<G, 256, 0, stream>>>(cur, rowstart, rowmid, indeg, col,
                                           in_norm, out_norm, W2, b2, Pf32, out);
    k_spmm<1, 1, 1><<<G, 256, 0, stream>>>(cur, rowstart, rowmid, indeg, col,
                                           in_norm, out_norm, W2, b2, Pf32, out);
}

// Round 18
// 465.480 us; speedup vs baseline: 1.3459x; 1.3459x over previous
//
#include <hip/hip_runtime.h>
#include <hip/hip_bf16.h>

#define NNODES 100000
#define NEDGES 3200000
#define INF 128
#define HID 32
#define NB 392                                 // buckets: node>>8, 256 nodes each
#define BSHIFT 8
#define NPB 256                                // nodes per bucket
#define BATCH 8192                             // edges per partition block
#define PART_BLOCKS ((NEDGES + BATCH - 1) / BATCH)  // 391
#define G1_ROWS 256                            // gemm1 rows per block
#define G1_KC 16                               // gemm1 k-chunk
#define G1_XP 260                              // padded xT row (words; mult of 4, %32=4)

typedef unsigned short u16;

__device__ __forceinline__ float blo(unsigned x) { return __uint_as_float(x << 16); }
__device__ __forceinline__ float bhi(unsigned x) { return __uint_as_float(x & 0xffff0000u); }
__device__ __forceinline__ u16 f2b(float f) {
    __hip_bfloat16 h = __float2bfloat16(f);    // RNE
    return *reinterpret_cast<u16*>(&h);
}

// ---- pass 1: per-block LDS bucket histograms -> global bucket counts ----
__global__ void k_cnt(const int* __restrict__ src, const int* __restrict__ dst,
                      int* __restrict__ bcnt_src, int* __restrict__ bcnt_dst) {
    __shared__ int hs[NB], hd[NB];
    int tid = threadIdx.x;
    for (int i = tid; i < NB; i += 1024) { hs[i] = 0; hd[i] = 0; }
    __syncthreads();
    int start = blockIdx.x * BATCH;
    int end = start + BATCH; if (end > NEDGES) end = NEDGES;
    for (int i = start + tid; i < end; i += 1024) {
        atomicAdd(&hs[src[i] >> BSHIFT], 1);
        atomicAdd(&hd[dst[i] >> BSHIFT], 1);
    }
    __syncthreads();
    for (int i = tid; i < NB; i += 1024) {
        if (hs[i]) atomicAdd(&bcnt_src[i], hs[i]);
        if (hd[i]) atomicAdd(&bcnt_dst[i], hd[i]);
    }
}

// ---- pass 2: exclusive scan of the NB-entry bucket counts (both sides) ----
__global__ void k_bscan(const int* __restrict__ bcnt_src, const int* __restrict__ bcnt_dst,
                        int* __restrict__ bbase_src, int* __restrict__ bbase_dst,
                        int* __restrict__ gcur_src, int* __restrict__ gcur_dst) {
    __shared__ int s[512], t[512];
    int tid = threadIdx.x;
    int vs = (tid < NB) ? bcnt_src[tid] : 0;
    int vd = (tid < NB) ? bcnt_dst[tid] : 0;
    s[tid] = vs; t[tid] = vd;
    __syncthreads();
    for (int off = 1; off < 512; off <<= 1) {
        int a = (tid >= off) ? s[tid - off] : 0;
        int b = (tid >= off) ? t[tid - off] : 0;
        __syncthreads();
        s[tid] += a; t[tid] += b;
        __syncthreads();
    }
    if (tid < NB) {
        bbase_src[tid] = s[tid] - vs;  gcur_src[tid] = s[tid] - vs;
        bbase_dst[tid] = t[tid] - vd;  gcur_dst[tid] = t[tid] - vd;
    }
}

// ---- pass 3: LDS-staged bucket partition (round-14 known-good) ----
__global__ void k_bucket2(const int* __restrict__ src, const int* __restrict__ dst,
                          int* __restrict__ gcur_src, int* __restrict__ gcur_dst,
                          int2* __restrict__ pairbuf, int* __restrict__ srctmp) {
    __shared__ int2 stage2[BATCH];             // 64 KB (phase B reuses as int[])
    __shared__ int cnt[NB], excl[NB], gbase[NB];
    __shared__ int sc[512];
    int* stage1 = (int*)stage2;
    int tid = threadIdx.x;                     // 1024 threads
    int start = blockIdx.x * BATCH;
    int end = start + BATCH; if (end > NEDGES) end = NEDGES;
    int cntE = end - start;

    int dd[8], sv[8], rk[8];

    // ================= Phase A: dst-bucketed (dst,src) pairs =================
    for (int i = tid; i < NB; i += 1024) cnt[i] = 0;
    __syncthreads();
#pragma unroll
    for (int k = 0; k < 8; ++k) {
        int i = start + tid + k * 1024;
        dd[k] = -1;
        if (i < end) {
            dd[k] = dst[i]; sv[k] = src[i];
            rk[k] = atomicAdd(&cnt[dd[k] >> BSHIFT], 1);
        }
    }
    __syncthreads();
    if (tid < 512) sc[tid] = (tid < NB) ? cnt[tid] : 0;
    __syncthreads();
    for (int off = 1; off < 512; off <<= 1) {
        int v = (tid < 512 && tid >= off) ? sc[tid - off] : 0;
        __syncthreads();
        if (tid < 512) sc[tid] += v;
        __syncthreads();
    }
    if (tid < NB) {
        excl[tid] = sc[tid] - cnt[tid];
        int c = cnt[tid];
        gbase[tid] = c ? atomicAdd(&gcur_dst[tid], c) : 0;
    }
    __syncthreads();
#pragma unroll
    for (int k = 0; k < 8; ++k)
        if (dd[k] >= 0) {
            int2 e; e.x = dd[k]; e.y = sv[k];
            stage2[excl[dd[k] >> BSHIFT] + rk[k]] = e;
        }
    __syncthreads();
    for (int j = tid; j < cntE; j += 1024) {
        int2 e = stage2[j];
        int b = e.x >> BSHIFT;
        pairbuf[gbase[b] + (j - excl[b])] = e;
    }
    __syncthreads();

    // ================= Phase B: src-bucketed src values ======================
    for (int i = tid; i < NB; i += 1024) cnt[i] = 0;
    __syncthreads();
#pragma unroll
    for (int k = 0; k < 8; ++k)
        if (dd[k] >= 0)
            rk[k] = atomicAdd(&cnt[sv[k] >> BSHIFT], 1);
    __syncthreads();
    if (tid < 512) sc[tid] = (tid < NB) ? cnt[tid] : 0;
    __syncthreads();
    for (int off = 1; off < 512; off <<= 1) {
        int v = (tid < 512 && tid >= off) ? sc[tid - off] : 0;
        __syncthreads();
        if (tid < 512) sc[tid] += v;
        __syncthreads();
    }
    if (tid < NB) {
        excl[tid] = sc[tid] - cnt[tid];
        int c = cnt[tid];
        gbase[tid] = c ? atomicAdd(&gcur_src[tid], c) : 0;
    }
    __syncthreads();
#pragma unroll
    for (int k = 0; k < 8; ++k)
        if (dd[k] >= 0)
            stage1[excl[sv[k] >> BSHIFT] + rk[k]] = sv[k];
    __syncthreads();
    for (int j = tid; j < cntE; j += 1024) {
        int v = stage1[j];
        int b = v >> BSHIFT;
        srctmp[gbase[b] + (j - excl[b])] = v;
    }
}

// ---- pass 4: per-bucket node stats. b<NB: src-phase (out_norm); else dst-phase
__global__ void k_nodes(const int* __restrict__ srctmp, const int2* __restrict__ pairbuf,
                        const int* __restrict__ bbase_src, const int* __restrict__ bcnt_src,
                        const int* __restrict__ bbase_dst, const int* __restrict__ bcnt_dst,
                        float* __restrict__ out_norm, float* __restrict__ in_norm,
                        int* __restrict__ indeg, int* __restrict__ rowstart) {
    __shared__ int cnt[NPB];
    __shared__ int ss[NPB];
    int tid = threadIdx.x;
    int b = blockIdx.x;
    int srcphase = (b < NB);
    int bb = srcphase ? b : b - NB;
    int node0 = bb * NPB;
    cnt[tid] = 0;
    __syncthreads();
    if (srcphase) {
        int s0 = bbase_src[bb], n = bcnt_src[bb];
        for (int i = tid; i < n; i += 256)
            atomicAdd(&cnt[srctmp[s0 + i] - node0], 1);
        __syncthreads();
        int nn = node0 + tid;
        if (nn < NNODES) {
            int c = cnt[tid];
            out_norm[nn] = rsqrtf((float)(c > 1 ? c : 1));
        }
    } else {
        int d0 = bbase_dst[bb], n = bcnt_dst[bb];
        for (int i = tid; i < n; i += 256)
            atomicAdd(&cnt[pairbuf[d0 + i].x - node0], 1);
        __syncthreads();
        int c = cnt[tid];
        ss[tid] = c;
        __syncthreads();
        for (int off = 1; off < 256; off <<= 1) {
            int t = (tid >= off) ? ss[tid - off] : 0;
            __syncthreads();
            ss[tid] += t;
            __syncthreads();
        }
        int excl = ss[tid] - c;
        int nn = node0 + tid;
        if (nn < NNODES) {
            indeg[nn] = c;
            in_norm[nn] = rsqrtf((float)(c > 1 ? c : 1));
            rowstart[nn] = d0 + excl;
        }
    }
}

// ---- pass 5: within-bucket placement; col window is one bucket (~32KB), L2-local --
__global__ void k_place(const int2* __restrict__ pairbuf, const int* __restrict__ rowstart,
                        int* __restrict__ col) {
    __shared__ int cur[NPB];
    int tid = threadIdx.x;
    int bucket = blockIdx.x;
    int node0 = bucket * NPB;
    if (node0 >= NNODES) return;
    int n = node0 + tid;
    cur[tid] = (n < NNODES) ? rowstart[n] : 0;
    __syncthreads();
    int pstart = rowstart[node0];
    int pend   = (node0 + NPB >= NNODES) ? NEDGES : rowstart[node0 + NPB];
    for (int i = pstart + tid; i < pend; i += 256) {
        int2 e = pairbuf[i];
        int pos = atomicAdd(&cur[e.x - node0], 1);
        col[pos] = e.y;
    }
}

// ---- conv1 dense: register-blocked. Thread tile = 4 rows x 8 cols (acc in VGPR).
// W1 in LDS [128][32]; x staged per 16-k chunk TRANSPOSED xT[16][260] via coalesced
// float4 loads. Per k: 1 ds_read_b128 (4 rows) + 2 ds_read_b128 (8 W cols,
// broadcast across row-groups) + 32 FMAs -> 32 FMA / 3 LDS instr.
__global__ __launch_bounds__(256) void k_gemm1(const float* __restrict__ x,
                                               const float* __restrict__ W1,
                                               const float* __restrict__ out_norm,
                                               u16* __restrict__ t) {
    __shared__ float wlds[INF * HID];          // 16 KB, [k][c]
    __shared__ float xT[G1_KC][G1_XP];         // 16.6 KB, transposed x chunk
    int tid = threadIdx.x;
    int row0 = blockIdx.x * G1_ROWS;
    for (int i = tid; i < INF * HID; i += 256) wlds[i] = W1[i];

    int rg = tid >> 2;                         // 0..63: row-group (4 rows)
    int cg = tid & 3;                          // 0..3: col-group (8 cols)
    int sr = tid >> 2;                         // staging row within pass
    int kq = tid & 3;                          // staging k-quad

    float acc[4][8];
#pragma unroll
    for (int r = 0; r < 4; ++r)
#pragma unroll
        for (int c = 0; c < 8; ++c) acc[r][c] = 0.f;

    for (int kc = 0; kc < INF; kc += G1_KC) {
        // stage xT: 256 rows x 16 k, coalesced 64B-per-4-lane reads
#pragma unroll
        for (int pass = 0; pass < 4; ++pass) {
            int r = pass * 64 + sr;
            int grow = row0 + r;
            float4 xv = make_float4(0.f, 0.f, 0.f, 0.f);
            if (grow < NNODES)
                xv = *(const float4*)(x + (size_t)grow * INF + kc + kq * 4);
            xT[kq * 4 + 0][r] = xv.x;
            xT[kq * 4 + 1][r] = xv.y;
            xT[kq * 4 + 2][r] = xv.z;
            xT[kq * 4 + 3][r] = xv.w;
        }
        __syncthreads();
#pragma unroll
        for (int kk = 0; kk < G1_KC; ++kk) {
            float4 xr = *(const float4*)&xT[kk][rg * 4];                  // 4 rows
            float4 wa = *(const float4*)&wlds[(kc + kk) * HID + cg * 8];  // cols 0-3
            float4 wb = *(const float4*)&wlds[(kc + kk) * HID + cg * 8 + 4];
            float xs[4] = {xr.x, xr.y, xr.z, xr.w};
#pragma unroll
            for (int r = 0; r < 4; ++r) {
                acc[r][0] = fmaf(xs[r], wa.x, acc[r][0]);
                acc[r][1] = fmaf(xs[r], wa.y, acc[r][1]);
                acc[r][2] = fmaf(xs[r], wa.z, acc[r][2]);
                acc[r][3] = fmaf(xs[r], wa.w, acc[r][3]);
                acc[r][4] = fmaf(xs[r], wb.x, acc[r][4]);
                acc[r][5] = fmaf(xs[r], wb.y, acc[r][5]);
                acc[r][6] = fmaf(xs[r], wb.z, acc[r][6]);
                acc[r][7] = fmaf(xs[r], wb.w, acc[r][7]);
            }
        }
        __syncthreads();                        // before next chunk overwrites xT
    }
#pragma unroll
    for (int r = 0; r < 4; ++r) {
        int row = row0 + rg * 4 + r;
        if (row < NNODES) {
            float on = out_norm[row];
            unsigned p0 = f2b(acc[r][0] * on) | ((unsigned)f2b(acc[r][1] * on) << 16);
            unsigned p1 = f2b(acc[r][2] * on) | ((unsigned)f2b(acc[r][3] * on) << 16);
            unsigned p2 = f2b(acc[r][4] * on) | ((unsigned)f2b(acc[r][5] * on) << 16);
            unsigned p3 = f2b(acc[r][6] * on) | ((unsigned)f2b(acc[r][7] * on) << 16);
            *(uint4*)(t + (size_t)row * HID + cg * 8) = make_uint4(p0, p1, p2, p3);
        }
    }
}

// ---------------- fused SpMM step — bf16 features, f32 math (round-11 known-good) --
template<int APPLY_W, int FINAL>
__global__ void k_spmm(const u16* __restrict__ gin, const int* __restrict__ rowstart,
                       const int* __restrict__ indeg, const int* __restrict__ col,
                       const float* __restrict__ in_norm, const float* __restrict__ out_norm,
                       const float* __restrict__ W, const float* __restrict__ bias,
                       void* __restrict__ gout) {
    __shared__ float wlds[HID * HID];          // 4 KB
    __shared__ float sh[8][HID];
    int tid = threadIdx.x, lane = tid & 31, group = tid >> 5;
    int g = lane >> 2, f = lane & 3;
    if (APPLY_W) {
        for (int i = tid; i < HID * HID; i += 256) wlds[i] = W[i];
        __syncthreads();
    }
    int n = blockIdx.x * 8 + group;            // grid = N/8 exact
    int start = rowstart[n];
    int deg   = indeg[n];
    const uint4* gin16 = (const uint4*)gin;    // 16B = 8 bf16

    float a[8];
#pragma unroll
    for (int j = 0; j < 8; ++j) a[j] = 0.f;

    int base = 0;
    for (; base + 32 <= deg; base += 32) {     // full chunks: no predication
        int c = col[start + base + lane];
#pragma unroll
        for (int t = 0; t < 4; ++t) {
            int s = __shfl(c, t * 8 + g, 32);
            uint4 v = gin16[(size_t)s * 4 + f];
            a[0] += blo(v.x); a[1] += bhi(v.x);
            a[2] += blo(v.y); a[3] += bhi(v.y);
            a[4] += blo(v.z); a[5] += bhi(v.z);
            a[6] += blo(v.w); a[7] += bhi(v.w);
        }
    }
    if (base < deg) {                          // tail chunk (rem in 1..31)
        int rem = deg - base;
        int c = (base + lane < deg) ? col[start + base + lane] : 0;
#pragma unroll
        for (int t = 0; t < 4; ++t) {
            if (t * 8 < rem) {
                int e = t * 8 + g;
                int s = __shfl(c, e, 32);
                uint4 v = gin16[(size_t)s * 4 + f];
                float m = (e < rem) ? 1.f : 0.f;
                a[0] = fmaf(m, blo(v.x), a[0]); a[1] = fmaf(m, bhi(v.x), a[1]);
                a[2] = fmaf(m, blo(v.y), a[2]); a[3] = fmaf(m, bhi(v.y), a[3]);
                a[4] = fmaf(m, blo(v.z), a[4]); a[5] = fmaf(m, bhi(v.z), a[5]);
                a[6] = fmaf(m, blo(v.w), a[6]); a[7] = fmaf(m, bhi(v.w), a[7]);
            }
        }
    }
    // reduce across the 8 edge-subgroups (lane bits 2,3,4)
#pragma unroll
    for (int j = 0; j < 8; ++j) {
        a[j] += __shfl_xor(a[j], 4, 32);
        a[j] += __shfl_xor(a[j], 8, 32);
        a[j] += __shfl_xor(a[j], 16, 32);
    }
    float inm = in_norm[n];
    if (g == 0) {                              // lanes 0..3 own feature quads
        float4 lo = make_float4(a[0] * inm, a[1] * inm, a[2] * inm, a[3] * inm);
        float4 hi = make_float4(a[4] * inm, a[5] * inm, a[6] * inm, a[7] * inm);
        *(float4*)&sh[group][f * 8]     = lo;  // same-wave LDS fill
        *(float4*)&sh[group][f * 8 + 4] = hi;
    }
    float res;
    if (APPLY_W) {
        float o = bias[lane];
#pragma unroll
        for (int k = 0; k < HID; ++k)
            o += sh[group][k] * wlds[k * HID + lane];
        res = o;
    } else {
        res = sh[group][lane] + bias[lane];
    }
    if (FINAL) ((float*)gout)[(size_t)n * HID + lane] = res;
    else       ((u16*)gout)[(size_t)n * HID + lane] = f2b(res * out_norm[n]);
}

extern "C" void kernel_launch(void* const* d_in, const int* in_sizes, int n_in,
                              void* d_out, int out_size, void* d_ws, size_t ws_size,
                              hipStream_t stream) {
    const float* in_feat = (const float*)d_in[0];
    const float* W1      = (const float*)d_in[1];
    const float* b1      = (const float*)d_in[2];
    const float* W2      = (const float*)d_in[3];
    const float* b2      = (const float*)d_in[4];
    const int*   src     = (const int*)d_in[5];
    const int*   dst     = (const int*)d_in[6];
    float*       out     = (float*)d_out;

    const int N = NNODES, E = NEDGES;
    // workspace layout (4-byte units)
    int* bcnt_src  = (int*)d_ws;                // 512
    int* bcnt_dst  = bcnt_src + 512;            // 512
    int* bbase_src = bcnt_dst + 512;            // 512
    int* bbase_dst = bbase_src + 512;           // 512
    int* gcur_src  = bbase_dst + 512;           // 512
    int* gcur_dst  = gcur_src + 512;            // 512
    int* indeg     = gcur_dst + 512;            // N
    int* rowstart  = indeg + N;                 // N
    float* out_norm = (float*)(rowstart + N);   // N
    float* in_norm  = out_norm + N;             // N
    int*   col      = (int*)(in_norm + N);      // E   (aliased as srctmp pre-place)
    void*  bufreg   = (void*)(col + E);         // E int2 region (pairbuf), later bf16 bufs
    int2*  pairbuf  = (int2*)bufreg;            // E pairs
    int*   srctmp   = col;                      // E ints, consumed before col written
    u16*   bufA16   = (u16*)bufreg;             // N*HID bf16 (6.4MB, fits in pairbuf region)
    u16*   bufB16   = bufA16 + (size_t)N * HID; // N*HID bf16
    size_t need = ((size_t)3072 + 4 * N + E + (size_t)2 * N * HID) * 4;
    if (ws_size < need) return;                 // fail visibly rather than corrupt

    hipMemsetAsync(bcnt_src, 0, 1024 * sizeof(int), stream);  // bcnt_src + bcnt_dst

    k_cnt    <<<PART_BLOCKS, 1024, 0, stream>>>(src, dst, bcnt_src, bcnt_dst);
    k_bscan  <<<1, 512, 0, stream>>>(bcnt_src, bcnt_dst, bbase_src, bbase_dst,
                                     gcur_src, gcur_dst);
    k_bucket2<<<PART_BLOCKS, 1024, 0, stream>>>(src, dst, gcur_src, gcur_dst,
                                                pairbuf, srctmp);
    k_nodes  <<<2 * NB, 256, 0, stream>>>(srctmp, pairbuf, bbase_src, bcnt_src,
                                          bbase_dst, bcnt_dst, out_norm, in_norm,
                                          indeg, rowstart);
    k_place  <<<NB, 256, 0, stream>>>(pairbuf, rowstart, col);

    // conv1 dense projection (weight_first since 128>32), bf16 output
    k_gemm1<<<(N + G1_ROWS - 1) / G1_ROWS, 256, 0, stream>>>(in_feat, W1, out_norm, bufA16);

    // conv1 aggregate: bufA -> bufB, res = agg*in_norm + b1, pre-scaled by out_norm
    k_spmm<0, 0><<<N / 8, 256, 0, stream>>>(bufA16, rowstart, indeg, col, in_norm,
                                            out_norm, W2, b1, bufB16);

    // 6 middle convs: ping-pong B->A->B->...
    u16* cur = bufB16; u16* nxt = bufA16;
    for (int i = 0; i < 6; ++i) {
        k_spmm<1, 0><<<N / 8, 256, 0, stream>>>(cur, rowstart, indeg, col, in_norm,
                                                out_norm, W2, b2, nxt);
        u16* tmp = cur; cur = nxt; nxt = tmp;
    }
    // final conv: cur -> out (f32, no out_norm pre-scale)
    k_spmm<1, 1><<<N / 8, 256, 0, stream>>>(cur, rowstart, indeg, col, in_norm,
                                            out_norm, W2, b2, out);
}